// Round 1
// baseline (504.546 us; speedup 1.0000x reference)
//
#include <hip/hip_runtime.h>
#include <hip/hip_bf16.h>
#include <stdint.h>

#define S_LEN 1024
#define E_DIM 768
#define H_N   12
#define FF_DIM 3072

typedef __hip_bfloat16 bf16;
using short8 = __attribute__((ext_vector_type(8))) short;
using f32x4  = __attribute__((ext_vector_type(4))) float;

__device__ __forceinline__ void async_cp16(const void* g, void* l) {
  __builtin_amdgcn_global_load_lds(
      (__attribute__((address_space(1))) void*)(g),
      (__attribute__((address_space(3))) void*)(l), 16, 0, 0);
}

// ---------------- weight transpose + cast: wt[n][k] = bf16(w[k][n]) ----------
__global__ __launch_bounds__(256) void wcastT(const float* __restrict__ w,
                                              bf16* __restrict__ wt,
                                              int K, int N) {
  __shared__ float t[32][33];
  int bx = blockIdx.x;          // n tile
  int by = blockIdx.y;          // k tile
  int x = threadIdx.x & 31;
  int y = threadIdx.x >> 5;     // 0..7
  for (int i = y; i < 32; i += 8)
    t[i][x] = w[(size_t)(by * 32 + i) * N + bx * 32 + x];
  __syncthreads();
  for (int i = y; i < 32; i += 8)
    wt[(size_t)(bx * 32 + i) * K + by * 32 + x] = __float2bfloat16(t[x][i]);
}

// ---------------- layernorm over E=768, out bf16 -----------------------------
__global__ __launch_bounds__(256) void ln_rows(const float* __restrict__ x,
                                               const float* __restrict__ g,
                                               const float* __restrict__ b,
                                               bf16* __restrict__ out) {
  int row = blockIdx.x;
  int tid = threadIdx.x;
  const float* xr = x + (size_t)row * E_DIM;
  float v0 = xr[tid], v1 = xr[tid + 256], v2 = xr[tid + 512];
  float s = v0 + v1 + v2;
  float ss = v0 * v0 + v1 * v1 + v2 * v2;
  for (int o = 32; o > 0; o >>= 1) {
    s  += __shfl_down(s, o);
    ss += __shfl_down(ss, o);
  }
  __shared__ float ps[4], pq[4];
  int wv = tid >> 6;
  if ((tid & 63) == 0) { ps[wv] = s; pq[wv] = ss; }
  __syncthreads();
  s  = ps[0] + ps[1] + ps[2] + ps[3];
  ss = pq[0] + pq[1] + pq[2] + pq[3];
  float mu  = s * (1.0f / E_DIM);
  float var = ss * (1.0f / E_DIM) - mu * mu;
  float rs  = rsqrtf(var + 1e-5f);
  bf16* orow = out + (size_t)row * E_DIM;
  orow[tid]       = __float2bfloat16((v0 - mu) * rs * g[tid]       + b[tid]);
  orow[tid + 256] = __float2bfloat16((v1 - mu) * rs * g[tid + 256] + b[tid + 256]);
  orow[tid + 512] = __float2bfloat16((v2 - mu) * rs * g[tid + 512] + b[tid + 512]);
}

// ---------------- m97-pattern GEMM: C[M,N] = A[M,K] @ Bt[N,K]^T --------------
// MODE 0: qkv scatter (q scaled 0.125 -> ob0 [N,H,S,D]; k -> ob1 [N,H,S,D];
//         v -> ob2 transposed [N,H,D,S])
// MODE 1/3: outf = acc + bias + resid (fp32)
// MODE 2: ob0 = bf16(gelu_exact(acc + bias))
template <int MODE>
__global__ __launch_bounds__(256) void gemm_bt(
    const bf16* __restrict__ A, const bf16* __restrict__ Bt,
    const float* __restrict__ bias, const float* __restrict__ resid,
    float* __restrict__ outf, bf16* __restrict__ ob0, bf16* __restrict__ ob1,
    bf16* __restrict__ ob2, int M, int N, int K) {
  __shared__ bf16 As[128 * 32];
  __shared__ bf16 Bs[128 * 32];
  int tid = threadIdx.x;
  int wave = tid >> 6, lane = tid & 63;
  int quad = lane >> 4, l16 = lane & 15;
  int m0 = blockIdx.y * 128, n0 = blockIdx.x * 128;
  int wm = (wave & 1) * 64, wn = (wave >> 1) * 64;
  f32x4 acc[4][4];
  for (int i = 0; i < 4; i++)
    for (int j = 0; j < 4; j++)
      for (int r = 0; r < 4; r++) acc[i][j][r] = 0.f;

  int lr = lane >> 2;         // 0..15: row within a 16-row issue
  int lc = (lane & 3) << 3;   // 0,8,16,24: k offset

  for (int kb = 0; kb < K; kb += 32) {
    __syncthreads();
    for (int t = 0; t < 2; ++t) {
      int rr = (t * 4 + wave) * 16;
      async_cp16(A  + (size_t)(m0 + rr + lr) * K + kb + lc, &As[rr * 32]);
      async_cp16(Bt + (size_t)(n0 + rr + lr) * K + kb + lc, &Bs[rr * 32]);
    }
    __syncthreads();
    short8 af[4], bfr[4];
    for (int i = 0; i < 4; i++)
      af[i] = *(const short8*)&As[(wm + i * 16 + l16) * 32 + quad * 8];
    for (int j = 0; j < 4; j++)
      bfr[j] = *(const short8*)&Bs[(wn + j * 16 + l16) * 32 + quad * 8];
    for (int i = 0; i < 4; i++)
      for (int j = 0; j < 4; j++)
        acc[i][j] = __builtin_amdgcn_mfma_f32_16x16x32_bf16(af[i], bfr[j],
                                                            acc[i][j], 0, 0, 0);
  }

  for (int i = 0; i < 4; i++) {
    for (int j = 0; j < 4; j++) {
      for (int r = 0; r < 4; r++) {
        int row = m0 + wm + i * 16 + quad * 4 + r;   // C/D layout (m89/m91)
        int col = n0 + wn + j * 16 + l16;
        float v = acc[i][j][r] + bias[col];
        if (MODE == 0) {
          int nn = row >> 10, s = row & 1023;
          if (col < 768) {
            ob0[(((size_t)nn * H_N + (col >> 6)) * S_LEN + s) * 64 + (col & 63)] =
                __float2bfloat16(v * 0.125f);
          } else if (col < 1536) {
            int c = col - 768;
            ob1[(((size_t)nn * H_N + (c >> 6)) * S_LEN + s) * 64 + (c & 63)] =
                __float2bfloat16(v);
          } else {
            int c = col - 1536;
            ob2[(((size_t)nn * H_N + (c >> 6)) * 64 + (c & 63)) * S_LEN + s] =
                __float2bfloat16(v);
          }
        } else if (MODE == 1 || MODE == 3) {
          size_t idx = (size_t)row * N + col;
          outf[idx] = v + resid[idx];
        } else if (MODE == 2) {
          float gel = 0.5f * v * (1.0f + erff(v * 0.70710678118654752f));
          ob0[(size_t)row * N + col] = __float2bfloat16(gel);
        }
      }
    }
  }
}

// ---------------- flash attention, causal; q pre-scaled ----------------------
// q,k: [N,H,S,64] bf16;  vt: [N,H,64,S] bf16;  out: [N,S,E] bf16
__global__ __launch_bounds__(256) void attn_fwd(
    const bf16* __restrict__ q, const bf16* __restrict__ k,
    const bf16* __restrict__ vt, bf16* __restrict__ out) {
  __shared__ bf16 kt[64 * 64];      // K rows [kpos][d]
  __shared__ bf16 vtile[64 * 64];   // Vt rows [d][kpos]
  __shared__ bf16 pb[4][16 * 64];   // per-wave P buffer
  int qt = blockIdx.x;              // q tile of 64
  int nh = blockIdx.y;              // n*H + h
  int n = nh / H_N, h = nh % H_N;
  int tid = threadIdx.x, wave = tid >> 6, lane = tid & 63;
  int quad = lane >> 4, l16 = lane & 15;
  const bf16* qp = q  + (size_t)nh * S_LEN * 64;
  const bf16* kp = k  + (size_t)nh * S_LEN * 64;
  const bf16* vp = vt + (size_t)nh * 64 * S_LEN;
  int qrow = qt * 64 + wave * 16;

  short8 qf[2];
  qf[0] = *(const short8*)&qp[(size_t)(qrow + l16) * 64 + quad * 8];
  qf[1] = *(const short8*)&qp[(size_t)(qrow + l16) * 64 + 32 + quad * 8];

  f32x4 oa[4];
  for (int d = 0; d < 4; d++)
    for (int r = 0; r < 4; r++) oa[d][r] = 0.f;
  float mi[4], li[4];
  for (int r = 0; r < 4; r++) { mi[r] = -INFINITY; li[r] = 0.f; }

  int lr = lane >> 3;          // 0..7
  int lc = (lane & 7) << 3;    // 0..56

  for (int kb = 0; kb <= qt; ++kb) {
    __syncthreads();
    for (int t = 0; t < 2; ++t) {
      int rr = (t * 4 + wave) * 8;
      async_cp16(kp + (size_t)(kb * 64 + rr + lr) * 64 + lc, &kt[rr * 64]);
      async_cp16(vp + (size_t)(rr + lr) * S_LEN + kb * 64 + lc, &vtile[rr * 64]);
    }
    __syncthreads();

    f32x4 sa[4];
    for (int nt = 0; nt < 4; nt++) {
      for (int r = 0; r < 4; r++) sa[nt][r] = 0.f;
      for (int ks = 0; ks < 2; ks++) {
        short8 kf = *(const short8*)&kt[(nt * 16 + l16) * 64 + ks * 32 + quad * 8];
        sa[nt] = __builtin_amdgcn_mfma_f32_16x16x32_bf16(qf[ks], kf, sa[nt], 0, 0, 0);
      }
    }
    if (kb == qt) {   // diagonal block: causal mask
      for (int nt = 0; nt < 4; nt++) {
        int kpos = kb * 64 + nt * 16 + l16;
        for (int r = 0; r < 4; r++) {
          int qg = qrow + quad * 4 + r;
          if (kpos > qg) sa[nt][r] = -INFINITY;
        }
      }
    }
    // online softmax; row = quad*4+r lives across the quad's 16 lanes
    for (int r = 0; r < 4; r++) {
      float mx = fmaxf(fmaxf(sa[0][r], sa[1][r]), fmaxf(sa[2][r], sa[3][r]));
      for (int o = 1; o < 16; o <<= 1) mx = fmaxf(mx, __shfl_xor(mx, o));
      float mn = fmaxf(mi[r], mx);
      float alpha = __expf(mi[r] - mn);
      float rs = 0.f;
      for (int nt = 0; nt < 4; nt++) {
        float p = __expf(sa[nt][r] - mn);
        sa[nt][r] = p;
        rs += p;
      }
      for (int o = 1; o < 16; o <<= 1) rs += __shfl_xor(rs, o);
      li[r] = li[r] * alpha + rs;
      mi[r] = mn;
      for (int d = 0; d < 4; d++) oa[d][r] *= alpha;
    }
    // P: C-layout -> A-layout via per-wave LDS round trip (m120 pattern)
    for (int nt = 0; nt < 4; nt++)
      for (int r = 0; r < 4; r++)
        pb[wave][(quad * 4 + r) * 64 + nt * 16 + l16] = __float2bfloat16(sa[nt][r]);
    __syncthreads();
    for (int ks = 0; ks < 2; ks++) {
      short8 pf = *(const short8*)&pb[wave][l16 * 64 + ks * 32 + quad * 8];
      for (int d = 0; d < 4; d++) {
        short8 vf = *(const short8*)&vtile[(d * 16 + l16) * 64 + ks * 32 + quad * 8];
        oa[d] = __builtin_amdgcn_mfma_f32_16x16x32_bf16(pf, vf, oa[d], 0, 0, 0);
      }
    }
  }
  for (int d = 0; d < 4; d++) {
    for (int r = 0; r < 4; r++) {
      int sg = qrow + quad * 4 + r;
      float val = oa[d][r] / li[r];
      out[((size_t)(n * S_LEN + sg)) * E_DIM + h * 64 + d * 16 + l16] =
          __float2bfloat16(val);
    }
  }
}

extern "C" void kernel_launch(void* const* d_in, const int* in_sizes, int n_in,
                              void* d_out, int out_size, void* d_ws, size_t ws_size,
                              hipStream_t stream) {
  (void)in_sizes; (void)n_in; (void)out_size; (void)ws_size;
  const float* x      = (const float*)d_in[0];
  const float* ln1_g  = (const float*)d_in[1];
  const float* ln1_b  = (const float*)d_in[2];
  const float* ln2_g  = (const float*)d_in[3];
  const float* ln2_b  = (const float*)d_in[4];
  const float* w_attn = (const float*)d_in[5];
  const float* b_attn = (const float*)d_in[6];
  const float* w_proj = (const float*)d_in[7];
  const float* b_proj = (const float*)d_in[8];
  const float* w_fc   = (const float*)d_in[9];
  const float* b_fc   = (const float*)d_in[10];
  const float* w_fc2  = (const float*)d_in[11];
  const float* b_fc2  = (const float*)d_in[12];
  float* out = (float*)d_out;

  char* ws = (char*)d_ws;
  bf16* wt_attn = (bf16*)(ws);                 //  3,538,944 B
  bf16* wt_proj = (bf16*)(ws + 3538944);       //  1,179,648 B
  bf16* wt_fc   = (bf16*)(ws + 4718592);       //  4,718,592 B
  bf16* wt_fc2  = (bf16*)(ws + 9437184);       //  4,718,592 B
  bf16* hbuf    = (bf16*)(ws + 14155776);      // 12,582,912 B
  float* x2     = (float*)(ws + 26738688);     // 25,165,824 B
  bf16* qb      = (bf16*)(ws + 51904512);      // 12,582,912 B
  bf16* kbuf    = (bf16*)(ws + 64487424);      // 12,582,912 B
  bf16* vtb     = (bf16*)(ws + 77070336);      // 12,582,912 B
  bf16* ao      = (bf16*)(ws + 89653248);      // 12,582,912 B  (ends 102,236,160)
  bf16* ff      = qb;  // reuse q/k/vt/ao region (50,331,648 B needed)

  dim3 blk(256);
  wcastT<<<dim3(2304 / 32, 768 / 32), blk, 0, stream>>>(w_attn, wt_attn, 768, 2304);
  wcastT<<<dim3(768 / 32, 768 / 32), blk, 0, stream>>>(w_proj, wt_proj, 768, 768);
  wcastT<<<dim3(3072 / 32, 768 / 32), blk, 0, stream>>>(w_fc, wt_fc, 768, 3072);
  wcastT<<<dim3(768 / 32, 3072 / 32), blk, 0, stream>>>(w_fc2, wt_fc2, 3072, 768);

  ln_rows<<<8192, blk, 0, stream>>>(x, ln1_g, ln1_b, hbuf);

  gemm_bt<0><<<dim3(2304 / 128, 8192 / 128), blk, 0, stream>>>(
      hbuf, wt_attn, b_attn, nullptr, nullptr, qb, kbuf, vtb, 8192, 2304, 768);

  attn_fwd<<<dim3(16, 96), blk, 0, stream>>>(qb, kbuf, vtb, ao);

  gemm_bt<1><<<dim3(768 / 128, 8192 / 128), blk, 0, stream>>>(
      ao, wt_proj, b_proj, x, x2, nullptr, nullptr, nullptr, 8192, 768, 768);

  ln_rows<<<8192, blk, 0, stream>>>(x2, ln2_g, ln2_b, hbuf);

  gemm_bt<2><<<dim3(3072 / 128, 8192 / 128), blk, 0, stream>>>(
      hbuf, wt_fc, b_fc, nullptr, nullptr, ff, nullptr, nullptr, 8192, 3072, 768);

  gemm_bt<3><<<dim3(768 / 128, 8192 / 128), blk, 0, stream>>>(
      ff, wt_fc2, b_fc2, x2, out, nullptr, nullptr, nullptr, 8192, 768, 3072);
}

// Round 2
// 445.155 us; speedup vs baseline: 1.1334x; 1.1334x over previous
//
#include <hip/hip_runtime.h>
#include <hip/hip_bf16.h>
#include <stdint.h>

#define S_LEN 1024
#define E_DIM 768
#define H_N   12
#define FF_DIM 3072

typedef __hip_bfloat16 bf16;
using short8  = __attribute__((ext_vector_type(8))) short;
using short4v = __attribute__((ext_vector_type(4))) short;
using f32x4   = __attribute__((ext_vector_type(4))) float;

__device__ __forceinline__ void async_cp16(const void* g, void* l) {
  __builtin_amdgcn_global_load_lds(
      (__attribute__((address_space(1))) void*)(g),
      (__attribute__((address_space(3))) void*)(l), 16, 0, 0);
}

// ---------------- weight transpose + cast: wt[n][k] = bf16(w[k][n]) ----------
__global__ __launch_bounds__(256) void wcastT(const float* __restrict__ w,
                                              bf16* __restrict__ wt,
                                              int K, int N) {
  __shared__ float t[32][33];
  int bx = blockIdx.x;          // n tile
  int by = blockIdx.y;          // k tile
  int x = threadIdx.x & 31;
  int y = threadIdx.x >> 5;     // 0..7
  for (int i = y; i < 32; i += 8)
    t[i][x] = w[(size_t)(by * 32 + i) * N + bx * 32 + x];
  __syncthreads();
  for (int i = y; i < 32; i += 8)
    wt[(size_t)(bx * 32 + i) * K + by * 32 + x] = __float2bfloat16(t[x][i]);
}

// ---------------- layernorm over E=768, out bf16 -----------------------------
__global__ __launch_bounds__(256) void ln_rows(const float* __restrict__ x,
                                               const float* __restrict__ g,
                                               const float* __restrict__ b,
                                               bf16* __restrict__ out) {
  int row = blockIdx.x;
  int tid = threadIdx.x;
  const float* xr = x + (size_t)row * E_DIM;
  float v0 = xr[tid], v1 = xr[tid + 256], v2 = xr[tid + 512];
  float s = v0 + v1 + v2;
  float ss = v0 * v0 + v1 * v1 + v2 * v2;
  for (int o = 32; o > 0; o >>= 1) {
    s  += __shfl_down(s, o);
    ss += __shfl_down(ss, o);
  }
  __shared__ float ps[4], pq[4];
  int wv = tid >> 6;
  if ((tid & 63) == 0) { ps[wv] = s; pq[wv] = ss; }
  __syncthreads();
  s  = ps[0] + ps[1] + ps[2] + ps[3];
  ss = pq[0] + pq[1] + pq[2] + pq[3];
  float mu  = s * (1.0f / E_DIM);
  float var = ss * (1.0f / E_DIM) - mu * mu;
  float rs  = rsqrtf(var + 1e-5f);
  bf16* orow = out + (size_t)row * E_DIM;
  orow[tid]       = __float2bfloat16((v0 - mu) * rs * g[tid]       + b[tid]);
  orow[tid + 256] = __float2bfloat16((v1 - mu) * rs * g[tid + 256] + b[tid + 256]);
  orow[tid + 512] = __float2bfloat16((v2 - mu) * rs * g[tid + 512] + b[tid + 512]);
}

// ---------------- m97-pattern GEMM: C[M,N] = A[M,K] @ Bt[N,K]^T --------------
// MODE 0: qkv scatter. q scaled 0.125 -> ob0 [nh][S][64].
//         k -> ob1 chunked [nh][8 dc][S=1024][8]  (elem (kpos,d) at
//              ((nh*8 + d/8)*1024 + kpos)*8 + d%8)
//         v -> ob2 chunked [nh][128 kc][64 d][8]  (elem (kpos,d) at
//              ((nh*128 + kpos/8)*64 + d)*8 + kpos%8)
// MODE 1/3: outf = acc + bias + resid (fp32)
// MODE 2: ob0 = bf16(gelu_exact(acc + bias))
template <int MODE>
__global__ __launch_bounds__(256) void gemm_bt(
    const bf16* __restrict__ A, const bf16* __restrict__ Bt,
    const float* __restrict__ bias, const float* __restrict__ resid,
    float* __restrict__ outf, bf16* __restrict__ ob0, bf16* __restrict__ ob1,
    bf16* __restrict__ ob2, int M, int N, int K) {
  __shared__ bf16 As[128 * 32];
  __shared__ bf16 Bs[128 * 32];
  int tid = threadIdx.x;
  int wave = tid >> 6, lane = tid & 63;
  int quad = lane >> 4, l16 = lane & 15;
  int m0 = blockIdx.y * 128, n0 = blockIdx.x * 128;
  int wm = (wave & 1) * 64, wn = (wave >> 1) * 64;
  f32x4 acc[4][4];
  for (int i = 0; i < 4; i++)
    for (int j = 0; j < 4; j++)
      for (int r = 0; r < 4; r++) acc[i][j][r] = 0.f;

  int lr = lane >> 2;         // 0..15: row within a 16-row issue
  int lc = (lane & 3) << 3;   // 0,8,16,24: k offset

  for (int kb = 0; kb < K; kb += 32) {
    __syncthreads();
    for (int t = 0; t < 2; ++t) {
      int rr = (t * 4 + wave) * 16;
      async_cp16(A  + (size_t)(m0 + rr + lr) * K + kb + lc, &As[rr * 32]);
      async_cp16(Bt + (size_t)(n0 + rr + lr) * K + kb + lc, &Bs[rr * 32]);
    }
    __syncthreads();
    short8 af[4], bfr[4];
    for (int i = 0; i < 4; i++)
      af[i] = *(const short8*)&As[(wm + i * 16 + l16) * 32 + quad * 8];
    for (int j = 0; j < 4; j++)
      bfr[j] = *(const short8*)&Bs[(wn + j * 16 + l16) * 32 + quad * 8];
    for (int i = 0; i < 4; i++)
      for (int j = 0; j < 4; j++)
        acc[i][j] = __builtin_amdgcn_mfma_f32_16x16x32_bf16(af[i], bfr[j],
                                                            acc[i][j], 0, 0, 0);
  }

  for (int i = 0; i < 4; i++) {
    for (int j = 0; j < 4; j++) {
      for (int r = 0; r < 4; r++) {
        int row = m0 + wm + i * 16 + quad * 4 + r;   // C/D layout (m89/m91)
        int col = n0 + wn + j * 16 + l16;
        float v = acc[i][j][r] + bias[col];
        if (MODE == 0) {
          int nn = row >> 10, s = row & 1023;
          if (col < 768) {
            ob0[(((size_t)nn * H_N + (col >> 6)) * S_LEN + s) * 64 + (col & 63)] =
                __float2bfloat16(v * 0.125f);
          } else if (col < 1536) {
            int c = col - 768;
            size_t nh2 = (size_t)nn * H_N + (c >> 6);
            int d = c & 63;
            ob1[((nh2 * 8 + (d >> 3)) * S_LEN + s) * 8 + (d & 7)] =
                __float2bfloat16(v);
          } else {
            int c = col - 1536;
            size_t nh2 = (size_t)nn * H_N + (c >> 6);
            int d = c & 63;
            ob2[((nh2 * 128 + (s >> 3)) * 64 + d) * 8 + (s & 7)] =
                __float2bfloat16(v);
          }
        } else if (MODE == 1 || MODE == 3) {
          size_t idx = (size_t)row * N + col;
          outf[idx] = v + resid[idx];
        } else if (MODE == 2) {
          float gel = 0.5f * v * (1.0f + erff(v * 0.70710678118654752f));
          ob0[(size_t)row * N + col] = __float2bfloat16(gel);
        }
      }
    }
  }
}

// ---------------- flash attention v2: S^T trick, causal; q pre-scaled --------
// q:  [nh][1024][64] bf16
// kg: [nh][8][1024][8]  chunked K
// vg: [nh][128][64][8]  chunked V (kpos-chunked)
// out: [N,S,E] bf16
__global__ __launch_bounds__(256) void attn_fwd(
    const bf16* __restrict__ q, const bf16* __restrict__ kg,
    const bf16* __restrict__ vg, bf16* __restrict__ out) {
  __shared__ bf16 kt2[8 * 64 * 8];   // [dc][kpos][8din]   8 KB
  __shared__ bf16 vt2[8 * 64 * 8];   // [kc][d][8kin]      8 KB
  __shared__ bf16 pb[4][16 * 68];    // per-wave P[q][kpos], stride 68 (pad)
  int qt = blockIdx.x;               // q tile of 64
  int nh = blockIdx.y;
  int n = nh / H_N, h = nh % H_N;
  int tid = threadIdx.x, wave = tid >> 6, lane = tid & 63;
  int quad = lane >> 4, l16 = lane & 15;
  const bf16* qp = q  + (size_t)nh * S_LEN * 64;
  const bf16* kp = kg + (size_t)nh * 8 * S_LEN * 8;
  const bf16* vp = vg + (size_t)nh * 128 * 64 * 8;
  int qrow = qt * 64 + wave * 16;    // wave's 16 q rows; lane's q = qrow + l16

  short8 qf[2];
  qf[0] = *(const short8*)&qp[(size_t)(qrow + l16) * 64 + quad * 8];
  qf[1] = *(const short8*)&qp[(size_t)(qrow + l16) * 64 + 32 + quad * 8];

  f32x4 oa[4];                       // O^T: d = dt*16+quad*4+r, q = l16
  for (int dt = 0; dt < 4; dt++)
    for (int r = 0; r < 4; r++) oa[dt][r] = 0.f;
  float mi = -INFINITY, li = 0.f;    // per-lane: one q row each

  for (int kb = 0; kb <= qt; ++kb) {
    __syncthreads();
    for (int t = 0; t < 2; ++t) {
      int s = t * 256 + tid;         // 16B slot index; uniform base + lane*16
      int c = s >> 6, e = s & 63;    // kt2: c=dchunk,e=kpos ; vt2: c=kchunk,e=d
      async_cp16(kp + ((size_t)c * S_LEN + kb * 64 + e) * 8, &kt2[(size_t)s * 8]);
      async_cp16(vp + ((size_t)(kb * 8 + c) * 64 + e) * 8, &vt2[(size_t)s * 8]);
    }
    __syncthreads();

    // S^T[kpos][q] = K·Q^T : lane holds q=l16, kpos = nt*16+quad*4+r
    f32x4 sa[4];
    for (int nt = 0; nt < 4; nt++) {
      for (int r = 0; r < 4; r++) sa[nt][r] = 0.f;
      for (int ks = 0; ks < 2; ks++) {
        short8 kf = *(const short8*)
            &kt2[(size_t)((ks * 4 + quad) * 64 + nt * 16 + l16) * 8];
        sa[nt] = __builtin_amdgcn_mfma_f32_16x16x32_bf16(kf, qf[ks], sa[nt], 0, 0, 0);
      }
    }
    if (kb == qt) {  // diagonal: mask kpos_local > q_local
      int ql = wave * 16 + l16;
      for (int nt = 0; nt < 4; nt++)
        for (int r = 0; r < 4; r++)
          if (nt * 16 + quad * 4 + r > ql) sa[nt][r] = -INFINITY;
    }
    // online softmax: all 16 score values for this lane's q are in-register;
    // full-64 reduction = 2 shuffles across quads (xor 16, 32)
    float mx = sa[0][0];
    for (int nt = 0; nt < 4; nt++)
      for (int r = 0; r < 4; r++) mx = fmaxf(mx, sa[nt][r]);
    mx = fmaxf(mx, __shfl_xor(mx, 16));
    mx = fmaxf(mx, __shfl_xor(mx, 32));
    float mn = fmaxf(mi, mx);
    float alpha = __expf(mi - mn);
    float rs = 0.f;
    for (int nt = 0; nt < 4; nt++)
      for (int r = 0; r < 4; r++) {
        float p = __expf(sa[nt][r] - mn);
        sa[nt][r] = p;
        rs += p;
      }
    rs += __shfl_xor(rs, 16);
    rs += __shfl_xor(rs, 32);
    li = li * alpha + rs;
    mi = mn;
    for (int dt = 0; dt < 4; dt++)
      for (int r = 0; r < 4; r++) oa[dt][r] *= alpha;

    // P write: lane's 4 regs of sa[nt] are 4 consecutive kpos for row q=l16
    bf16* pw = pb[wave];
    for (int nt = 0; nt < 4; nt++) {
      short4v pk;
      for (int r = 0; r < 4; r++)
        pk[r] = __builtin_bit_cast(short, __float2bfloat16(sa[nt][r]));
      *(short4v*)&pw[l16 * 68 + nt * 16 + quad * 4] = pk;
    }
    asm volatile("s_waitcnt lgkmcnt(0)" ::: "memory");  // same-wave LDS RAW

    // O^T[d][q] += V^T·P^T : A = V^T frag (chunked vt2), B = P row-major frag
    for (int ks = 0; ks < 2; ks++) {
      short8 pf = *(const short8*)&pw[l16 * 68 + ks * 32 + quad * 8];
      for (int dt = 0; dt < 4; dt++) {
        short8 vf = *(const short8*)
            &vt2[(size_t)((ks * 4 + quad) * 64 + dt * 16 + l16) * 8];
        oa[dt] = __builtin_amdgcn_mfma_f32_16x16x32_bf16(vf, pf, oa[dt], 0, 0, 0);
      }
    }
  }

  float inv = 1.0f / li;
  int token = n * S_LEN + qrow + l16;
  for (int dt = 0; dt < 4; dt++) {
    short4v ov;
    for (int r = 0; r < 4; r++)
      ov[r] = __builtin_bit_cast(short, __float2bfloat16(oa[dt][r] * inv));
    *(short4v*)&out[(size_t)token * E_DIM + h * 64 + dt * 16 + quad * 4] = ov;
  }
}

extern "C" void kernel_launch(void* const* d_in, const int* in_sizes, int n_in,
                              void* d_out, int out_size, void* d_ws, size_t ws_size,
                              hipStream_t stream) {
  (void)in_sizes; (void)n_in; (void)out_size; (void)ws_size;
  const float* x      = (const float*)d_in[0];
  const float* ln1_g  = (const float*)d_in[1];
  const float* ln1_b  = (const float*)d_in[2];
  const float* ln2_g  = (const float*)d_in[3];
  const float* ln2_b  = (const float*)d_in[4];
  const float* w_attn = (const float*)d_in[5];
  const float* b_attn = (const float*)d_in[6];
  const float* w_proj = (const float*)d_in[7];
  const float* b_proj = (const float*)d_in[8];
  const float* w_fc   = (const float*)d_in[9];
  const float* b_fc   = (const float*)d_in[10];
  const float* w_fc2  = (const float*)d_in[11];
  const float* b_fc2  = (const float*)d_in[12];
  float* out = (float*)d_out;

  char* ws = (char*)d_ws;
  bf16* wt_attn = (bf16*)(ws);                 //  3,538,944 B
  bf16* wt_proj = (bf16*)(ws + 3538944);       //  1,179,648 B
  bf16* wt_fc   = (bf16*)(ws + 4718592);       //  4,718,592 B
  bf16* wt_fc2  = (bf16*)(ws + 9437184);       //  4,718,592 B
  bf16* hbuf    = (bf16*)(ws + 14155776);      // 12,582,912 B
  float* x2     = (float*)(ws + 26738688);     // 25,165,824 B
  bf16* qb      = (bf16*)(ws + 51904512);      // 12,582,912 B
  bf16* kbuf    = (bf16*)(ws + 64487424);      // 12,582,912 B (chunked kg)
  bf16* vtb     = (bf16*)(ws + 77070336);      // 12,582,912 B (chunked vg)
  bf16* ao      = (bf16*)(ws + 89653248);      // 12,582,912 B  (ends 102,236,160)
  bf16* ff      = qb;  // reuse q/k/v/ao region (50,331,648 B needed)

  dim3 blk(256);
  wcastT<<<dim3(2304 / 32, 768 / 32), blk, 0, stream>>>(w_attn, wt_attn, 768, 2304);
  wcastT<<<dim3(768 / 32, 768 / 32), blk, 0, stream>>>(w_proj, wt_proj, 768, 768);
  wcastT<<<dim3(3072 / 32, 768 / 32), blk, 0, stream>>>(w_fc, wt_fc, 768, 3072);
  wcastT<<<dim3(768 / 32, 3072 / 32), blk, 0, stream>>>(w_fc2, wt_fc2, 3072, 768);

  ln_rows<<<8192, blk, 0, stream>>>(x, ln1_g, ln1_b, hbuf);

  gemm_bt<0><<<dim3(2304 / 128, 8192 / 128), blk, 0, stream>>>(
      hbuf, wt_attn, b_attn, nullptr, nullptr, qb, kbuf, vtb, 8192, 2304, 768);

  attn_fwd<<<dim3(16, 96), blk, 0, stream>>>(qb, kbuf, vtb, ao);

  gemm_bt<1><<<dim3(768 / 128, 8192 / 128), blk, 0, stream>>>(
      ao, wt_proj, b_proj, x, x2, nullptr, nullptr, nullptr, 8192, 768, 768);

  ln_rows<<<8192, blk, 0, stream>>>(x2, ln2_g, ln2_b, hbuf);

  gemm_bt<2><<<dim3(3072 / 128, 8192 / 128), blk, 0, stream>>>(
      hbuf, wt_fc, b_fc, nullptr, nullptr, ff, nullptr, nullptr, 8192, 3072, 768);

  gemm_bt<3><<<dim3(768 / 128, 8192 / 128), blk, 0, stream>>>(
      ff, wt_fc2, b_fc2, x2, out, nullptr, nullptr, nullptr, 8192, 768, 3072);
}

// Round 4
// 434.216 us; speedup vs baseline: 1.1620x; 1.0252x over previous
//
#include <hip/hip_runtime.h>
#include <hip/hip_bf16.h>
#include <stdint.h>

#define S_LEN 1024
#define E_DIM 768
#define H_N   12
#define FF_DIM 3072

typedef __hip_bfloat16 bf16;
using short8  = __attribute__((ext_vector_type(8))) short;
using short4v = __attribute__((ext_vector_type(4))) short;
using f32x4   = __attribute__((ext_vector_type(4))) float;

__device__ __forceinline__ void async_cp16(const void* g, void* l) {
  __builtin_amdgcn_global_load_lds(
      (__attribute__((address_space(1))) void*)(g),
      (__attribute__((address_space(3))) void*)(l), 16, 0, 0);
}

// ---------------- weight transpose + cast: wt[n][k] = bf16(w[k][n]) ----------
__global__ __launch_bounds__(256) void wcastT(const float* __restrict__ w,
                                              bf16* __restrict__ wt,
                                              int K, int N) {
  __shared__ float t[32][33];
  int bx = blockIdx.x;          // n tile
  int by = blockIdx.y;          // k tile
  int x = threadIdx.x & 31;
  int y = threadIdx.x >> 5;     // 0..7
  for (int i = y; i < 32; i += 8)
    t[i][x] = w[(size_t)(by * 32 + i) * N + bx * 32 + x];
  __syncthreads();
  for (int i = y; i < 32; i += 8)
    wt[(size_t)(bx * 32 + i) * K + by * 32 + x] = __float2bfloat16(t[x][i]);
}

// ---------------- layernorm over E=768, out bf16 -----------------------------
__global__ __launch_bounds__(256) void ln_rows(const float* __restrict__ x,
                                               const float* __restrict__ g,
                                               const float* __restrict__ b,
                                               bf16* __restrict__ out) {
  int row = blockIdx.x;
  int tid = threadIdx.x;
  const float* xr = x + (size_t)row * E_DIM;
  float v0 = xr[tid], v1 = xr[tid + 256], v2 = xr[tid + 512];
  float s = v0 + v1 + v2;
  float ss = v0 * v0 + v1 * v1 + v2 * v2;
  for (int o = 32; o > 0; o >>= 1) {
    s  += __shfl_down(s, o);
    ss += __shfl_down(ss, o);
  }
  __shared__ float ps[4], pq[4];
  int wv = tid >> 6;
  if ((tid & 63) == 0) { ps[wv] = s; pq[wv] = ss; }
  __syncthreads();
  s  = ps[0] + ps[1] + ps[2] + ps[3];
  ss = pq[0] + pq[1] + pq[2] + pq[3];
  float mu  = s * (1.0f / E_DIM);
  float var = ss * (1.0f / E_DIM) - mu * mu;
  float rs  = rsqrtf(var + 1e-5f);
  bf16* orow = out + (size_t)row * E_DIM;
  orow[tid]       = __float2bfloat16((v0 - mu) * rs * g[tid]       + b[tid]);
  orow[tid + 256] = __float2bfloat16((v1 - mu) * rs * g[tid + 256] + b[tid + 256]);
  orow[tid + 512] = __float2bfloat16((v2 - mu) * rs * g[tid + 512] + b[tid + 512]);
}

// ---------------- m97-pattern GEMM: C[M,N] = A[M,K] @ Bt[N,K]^T --------------
// MFMA operands SWAPPED (mfma(bfr, af)) so D holds C^T fragments:
//   lane's 4 acc regs = 4 consecutive N-cols of one M-row
//   row(M) = m0+wm+i*16+l16 ; col(N) = n0+wn+j*16+quad*4+r
// MODE 0: qkv scatter. q scaled 0.125 -> ob0 [nh][S][64] (short4 stores).
//         k -> ob1 chunked [nh][8 dc][S][8] (short4); v -> ob2 chunked
//         [nh][128 kc][64 d][8] (scalar).
// MODE 1/3: outf = acc + bias + resid (float4 in/out)
// MODE 2: ob0 = bf16(gelu_tanh(acc + bias)) (short4 stores)
template <int MODE>
__global__ __launch_bounds__(256) void gemm_bt(
    const bf16* __restrict__ A, const bf16* __restrict__ Bt,
    const float* __restrict__ bias, const float* __restrict__ resid,
    float* __restrict__ outf, bf16* __restrict__ ob0, bf16* __restrict__ ob1,
    bf16* __restrict__ ob2, int M, int N, int K) {
  __shared__ bf16 As[128 * 32];
  __shared__ bf16 Bs[128 * 32];
  int tid = threadIdx.x;
  int wave = tid >> 6, lane = tid & 63;
  int quad = lane >> 4, l16 = lane & 15;
  int m0 = blockIdx.y * 128, n0 = blockIdx.x * 128;
  int wm = (wave & 1) * 64, wn = (wave >> 1) * 64;
  f32x4 acc[4][4];
  for (int i = 0; i < 4; i++)
    for (int j = 0; j < 4; j++)
      for (int r = 0; r < 4; r++) acc[i][j][r] = 0.f;

  int lr = lane >> 2;         // 0..15: row within a 16-row issue
  int lc = (lane & 3) << 3;   // 0,8,16,24: k offset

  for (int kb = 0; kb < K; kb += 32) {
    __syncthreads();
    for (int t = 0; t < 2; ++t) {
      int rr = (t * 4 + wave) * 16;
      async_cp16(A  + (size_t)(m0 + rr + lr) * K + kb + lc, &As[rr * 32]);
      async_cp16(Bt + (size_t)(n0 + rr + lr) * K + kb + lc, &Bs[rr * 32]);
    }
    __syncthreads();
    short8 af[4], bfr[4];
    for (int i = 0; i < 4; i++)
      af[i] = *(const short8*)&As[(wm + i * 16 + l16) * 32 + quad * 8];
    for (int j = 0; j < 4; j++)
      bfr[j] = *(const short8*)&Bs[(wn + j * 16 + l16) * 32 + quad * 8];
    for (int i = 0; i < 4; i++)
      for (int j = 0; j < 4; j++)
        acc[i][j] = __builtin_amdgcn_mfma_f32_16x16x32_bf16(bfr[j], af[i],
                                                            acc[i][j], 0, 0, 0);
  }

  for (int j = 0; j < 4; j++) {
    int colb = n0 + wn + j * 16 + quad * 4;          // 4 consecutive cols
    f32x4 b4 = *(const f32x4*)&bias[colb];
    for (int i = 0; i < 4; i++) {
      int row = m0 + wm + i * 16 + l16;
      f32x4 v = acc[i][j] + b4;
      if (MODE == 0) {
        int nn = row >> 10, s = row & 1023;
        if (colb < 768) {
          int h = colb >> 6, db = colb & 63;
          short4v pk;
          for (int r = 0; r < 4; r++)
            pk[r] = __builtin_bit_cast(short, __float2bfloat16(v[r] * 0.125f));
          *(short4v*)&ob0[(((size_t)nn * H_N + h) * S_LEN + s) * 64 + db] = pk;
        } else if (colb < 1536) {
          int c = colb - 768;
          size_t nh2 = (size_t)nn * H_N + (c >> 6);
          int d = c & 63;
          short4v pk;
          for (int r = 0; r < 4; r++)
            pk[r] = __builtin_bit_cast(short, __float2bfloat16(v[r]));
          *(short4v*)&ob1[((nh2 * 8 + (d >> 3)) * S_LEN + s) * 8 + (d & 7)] = pk;
        } else {
          int c = colb - 1536;
          size_t nh2 = (size_t)nn * H_N + (c >> 6);
          int d0 = c & 63;
          for (int r = 0; r < 4; r++)
            ob2[((nh2 * 128 + (s >> 3)) * 64 + d0 + r) * 8 + (s & 7)] =
                __float2bfloat16(v[r]);
        }
      } else if (MODE == 1 || MODE == 3) {
        size_t idx = (size_t)row * N + colb;
        f32x4 rv = *(const f32x4*)&resid[idx];
        *(f32x4*)&outf[idx] = v + rv;
      } else if (MODE == 2) {
        short4v pk;
        for (int r = 0; r < 4; r++) {
          float x = v[r];
          // tanh-form GELU: x * sigmoid(1.5957691*(x + 0.044715 x^3))
          float t = x * (1.59576912161f + 0.0713548162726f * x * x);
          float g = x * __builtin_amdgcn_rcpf(1.0f + __expf(-t));
          pk[r] = __builtin_bit_cast(short, __float2bfloat16(g));
        }
        *(short4v*)&ob0[(size_t)row * N + colb] = pk;
      }
    }
  }
}

// ---------------- flash attention v2: S^T trick, causal; q pre-scaled --------
// q:  [nh][1024][64] bf16
// kg: [nh][8][1024][8]  chunked K
// vg: [nh][128][64][8]  chunked V (kpos-chunked)
// out: [N,S,E] bf16
__global__ __launch_bounds__(256) void attn_fwd(
    const bf16* __restrict__ q, const bf16* __restrict__ kg,
    const bf16* __restrict__ vg, bf16* __restrict__ out) {
  __shared__ bf16 kt2[8 * 64 * 8];   // [dc][kpos][8din]   8 KB
  __shared__ bf16 vt2[8 * 64 * 8];   // [kc][d][8kin]      8 KB
  __shared__ bf16 pb[4][16 * 68];    // per-wave P[q][kpos], stride 68 (pad)
  int qt = blockIdx.x;               // q tile of 64
  int nh = blockIdx.y;
  int n = nh / H_N, h = nh % H_N;
  int tid = threadIdx.x, wave = tid >> 6, lane = tid & 63;
  int quad = lane >> 4, l16 = lane & 15;
  const bf16* qp = q  + (size_t)nh * S_LEN * 64;
  const bf16* kp = kg + (size_t)nh * 8 * S_LEN * 8;
  const bf16* vp = vg + (size_t)nh * 128 * 64 * 8;
  int qrow = qt * 64 + wave * 16;    // wave's 16 q rows; lane's q = qrow + l16

  short8 qf[2];
  qf[0] = *(const short8*)&qp[(size_t)(qrow + l16) * 64 + quad * 8];
  qf[1] = *(const short8*)&qp[(size_t)(qrow + l16) * 64 + 32 + quad * 8];

  f32x4 oa[4];                       // O^T: d = dt*16+quad*4+r, q = l16
  for (int dt = 0; dt < 4; dt++)
    for (int r = 0; r < 4; r++) oa[dt][r] = 0.f;
  float mi = -INFINITY, li = 0.f;    // per-lane: one q row each

  for (int kb = 0; kb <= qt; ++kb) {
    __syncthreads();
    for (int t = 0; t < 2; ++t) {
      int s = t * 256 + tid;         // 16B slot index; uniform base + lane*16
      int c = s >> 6, e = s & 63;    // kt2: c=dchunk,e=kpos ; vt2: c=kchunk,e=d
      async_cp16(kp + ((size_t)c * S_LEN + kb * 64 + e) * 8, &kt2[(size_t)s * 8]);
      async_cp16(vp + ((size_t)(kb * 8 + c) * 64 + e) * 8, &vt2[(size_t)s * 8]);
    }
    __syncthreads();

    // S^T[kpos][q] = K·Q^T : lane holds q=l16, kpos = nt*16+quad*4+r
    f32x4 sa[4];
    for (int nt = 0; nt < 4; nt++) {
      for (int r = 0; r < 4; r++) sa[nt][r] = 0.f;
      for (int ks = 0; ks < 2; ks++) {
        short8 kf = *(const short8*)
            &kt2[(size_t)((ks * 4 + quad) * 64 + nt * 16 + l16) * 8];
        sa[nt] = __builtin_amdgcn_mfma_f32_16x16x32_bf16(kf, qf[ks], sa[nt], 0, 0, 0);
      }
    }
    if (kb == qt) {  // diagonal: mask kpos_local > q_local
      int ql = wave * 16 + l16;
      for (int nt = 0; nt < 4; nt++)
        for (int r = 0; r < 4; r++)
          if (nt * 16 + quad * 4 + r > ql) sa[nt][r] = -INFINITY;
    }
    // online softmax: all 16 score values for this lane's q are in-register;
    // full-64 reduction = 2 shuffles across quads (xor 16, 32)
    float mx = sa[0][0];
    for (int nt = 0; nt < 4; nt++)
      for (int r = 0; r < 4; r++) mx = fmaxf(mx, sa[nt][r]);
    mx = fmaxf(mx, __shfl_xor(mx, 16));
    mx = fmaxf(mx, __shfl_xor(mx, 32));
    float mn = fmaxf(mi, mx);
    float alpha = __expf(mi - mn);
    float rs = 0.f;
    for (int nt = 0; nt < 4; nt++)
      for (int r = 0; r < 4; r++) {
        float p = __expf(sa[nt][r] - mn);
        sa[nt][r] = p;
        rs += p;
      }
    rs += __shfl_xor(rs, 16);
    rs += __shfl_xor(rs, 32);
    li = li * alpha + rs;
    mi = mn;
    for (int dt = 0; dt < 4; dt++)
      for (int r = 0; r < 4; r++) oa[dt][r] *= alpha;

    // P write: lane's 4 regs of sa[nt] are 4 consecutive kpos for row q=l16
    bf16* pw = pb[wave];
    for (int nt = 0; nt < 4; nt++) {
      short4v pk;
      for (int r = 0; r < 4; r++)
        pk[r] = __builtin_bit_cast(short, __float2bfloat16(sa[nt][r]));
      *(short4v*)&pw[l16 * 68 + nt * 16 + quad * 4] = pk;
    }
    asm volatile("s_waitcnt lgkmcnt(0)" ::: "memory");  // same-wave LDS RAW

    // O^T[d][q] += V^T·P^T : A = V^T frag (chunked vt2), B = P row-major frag
    for (int ks = 0; ks < 2; ks++) {
      short8 pf = *(const short8*)&pw[l16 * 68 + ks * 32 + quad * 8];
      for (int dt = 0; dt < 4; dt++) {
        short8 vf = *(const short8*)
            &vt2[(size_t)((ks * 4 + quad) * 64 + dt * 16 + l16) * 8];
        oa[dt] = __builtin_amdgcn_mfma_f32_16x16x32_bf16(vf, pf, oa[dt], 0, 0, 0);
      }
    }
  }

  float inv = 1.0f / li;
  int token = n * S_LEN + qrow + l16;
  for (int dt = 0; dt < 4; dt++) {
    short4v ov;
    for (int r = 0; r < 4; r++)
      ov[r] = __builtin_bit_cast(short, __float2bfloat16(oa[dt][r] * inv));
    *(short4v*)&out[(size_t)token * E_DIM + h * 64 + dt * 16 + quad * 4] = ov;
  }
}

extern "C" void kernel_launch(void* const* d_in, const int* in_sizes, int n_in,
                              void* d_out, int out_size, void* d_ws, size_t ws_size,
                              hipStream_t stream) {
  (void)in_sizes; (void)n_in; (void)out_size; (void)ws_size;
  const float* x      = (const float*)d_in[0];
  const float* ln1_g  = (const float*)d_in[1];
  const float* ln1_b  = (const float*)d_in[2];
  const float* ln2_g  = (const float*)d_in[3];
  const float* ln2_b  = (const float*)d_in[4];
  const float* w_attn = (const float*)d_in[5];
  const float* b_attn = (const float*)d_in[6];
  const float* w_proj = (const float*)d_in[7];
  const float* b_proj = (const float*)d_in[8];
  const float* w_fc   = (const float*)d_in[9];
  const float* b_fc   = (const float*)d_in[10];
  const float* w_fc2  = (const float*)d_in[11];
  const float* b_fc2  = (const float*)d_in[12];
  float* out = (float*)d_out;

  char* ws = (char*)d_ws;
  bf16* wt_attn = (bf16*)(ws);                 //  3,538,944 B
  bf16* wt_proj = (bf16*)(ws + 3538944);       //  1,179,648 B
  bf16* wt_fc   = (bf16*)(ws + 4718592);       //  4,718,592 B
  bf16* wt_fc2  = (bf16*)(ws + 9437184);       //  4,718,592 B
  bf16* hbuf    = (bf16*)(ws + 14155776);      // 12,582,912 B
  float* x2     = (float*)(ws + 26738688);     // 25,165,824 B
  bf16* qb      = (bf16*)(ws + 51904512);      // 12,582,912 B
  bf16* kbuf    = (bf16*)(ws + 64487424);      // 12,582,912 B (chunked kg)
  bf16* vtb     = (bf16*)(ws + 77070336);      // 12,582,912 B (chunked vg)
  bf16* ao      = (bf16*)(ws + 89653248);      // 12,582,912 B  (ends 102,236,160)
  bf16* ff      = qb;  // reuse q/k/v/ao region (50,331,648 B needed)

  dim3 blk(256);
  wcastT<<<dim3(2304 / 32, 768 / 32), blk, 0, stream>>>(w_attn, wt_attn, 768, 2304);
  wcastT<<<dim3(768 / 32, 768 / 32), blk, 0, stream>>>(w_proj, wt_proj, 768, 768);
  wcastT<<<dim3(3072 / 32, 768 / 32), blk, 0, stream>>>(w_fc, wt_fc, 768, 3072);
  wcastT<<<dim3(768 / 32, 3072 / 32), blk, 0, stream>>>(w_fc2, wt_fc2, 3072, 768);

  ln_rows<<<8192, blk, 0, stream>>>(x, ln1_g, ln1_b, hbuf);

  gemm_bt<0><<<dim3(2304 / 128, 8192 / 128), blk, 0, stream>>>(
      hbuf, wt_attn, b_attn, nullptr, nullptr, qb, kbuf, vtb, 8192, 2304, 768);

  attn_fwd<<<dim3(16, 96), blk, 0, stream>>>(qb, kbuf, vtb, ao);

  gemm_bt<1><<<dim3(768 / 128, 8192 / 128), blk, 0, stream>>>(
      ao, wt_proj, b_proj, x, x2, nullptr, nullptr, nullptr, 8192, 768, 768);

  ln_rows<<<8192, blk, 0, stream>>>(x2, ln2_g, ln2_b, hbuf);

  gemm_bt<2><<<dim3(3072 / 128, 8192 / 128), blk, 0, stream>>>(
      hbuf, wt_fc, b_fc, nullptr, nullptr, ff, nullptr, nullptr, 8192, 3072, 768);

  gemm_bt<3><<<dim3(768 / 128, 8192 / 128), blk, 0, stream>>>(
      ff, wt_fc2, b_fc2, x2, out, nullptr, nullptr, nullptr, 8192, 768, 3072);
}

// Round 5
// 372.896 us; speedup vs baseline: 1.3530x; 1.1644x over previous
//
#include <hip/hip_runtime.h>
#include <hip/hip_bf16.h>
#include <stdint.h>

#define S_LEN 1024
#define E_DIM 768
#define H_N   12
#define FF_DIM 3072

typedef __hip_bfloat16 bf16;
using short8  = __attribute__((ext_vector_type(8))) short;
using short4v = __attribute__((ext_vector_type(4))) short;
using f32x4   = __attribute__((ext_vector_type(4))) float;

__device__ __forceinline__ void async_cp16(const void* g, void* l) {
  __builtin_amdgcn_global_load_lds(
      (__attribute__((address_space(1))) void*)(g),
      (__attribute__((address_space(3))) void*)(l), 16, 0, 0);
}

// ---------------- weight transpose + cast: wt[n][k] = bf16(w[k][n]) ----------
__global__ __launch_bounds__(256) void wcastT(const float* __restrict__ w,
                                              bf16* __restrict__ wt,
                                              int K, int N) {
  __shared__ float t[32][33];
  int bx = blockIdx.x;          // n tile
  int by = blockIdx.y;          // k tile
  int x = threadIdx.x & 31;
  int y = threadIdx.x >> 5;     // 0..7
  for (int i = y; i < 32; i += 8)
    t[i][x] = w[(size_t)(by * 32 + i) * N + bx * 32 + x];
  __syncthreads();
  for (int i = y; i < 32; i += 8)
    wt[(size_t)(bx * 32 + i) * K + by * 32 + x] = __float2bfloat16(t[x][i]);
}

// ---------------- layernorm over E=768, out bf16 -----------------------------
__global__ __launch_bounds__(256) void ln_rows(const float* __restrict__ x,
                                               const float* __restrict__ g,
                                               const float* __restrict__ b,
                                               bf16* __restrict__ out) {
  int row = blockIdx.x;
  int tid = threadIdx.x;
  const float* xr = x + (size_t)row * E_DIM;
  float v0 = xr[tid], v1 = xr[tid + 256], v2 = xr[tid + 512];
  float s = v0 + v1 + v2;
  float ss = v0 * v0 + v1 * v1 + v2 * v2;
  for (int o = 32; o > 0; o >>= 1) {
    s  += __shfl_down(s, o);
    ss += __shfl_down(ss, o);
  }
  __shared__ float ps[4], pq[4];
  int wv = tid >> 6;
  if ((tid & 63) == 0) { ps[wv] = s; pq[wv] = ss; }
  __syncthreads();
  s  = ps[0] + ps[1] + ps[2] + ps[3];
  ss = pq[0] + pq[1] + pq[2] + pq[3];
  float mu  = s * (1.0f / E_DIM);
  float var = ss * (1.0f / E_DIM) - mu * mu;
  float rs  = rsqrtf(var + 1e-5f);
  bf16* orow = out + (size_t)row * E_DIM;
  orow[tid]       = __float2bfloat16((v0 - mu) * rs * g[tid]       + b[tid]);
  orow[tid + 256] = __float2bfloat16((v1 - mu) * rs * g[tid + 256] + b[tid + 256]);
  orow[tid + 512] = __float2bfloat16((v2 - mu) * rs * g[tid + 512] + b[tid + 512]);
}

// ---------------- GEMM: C[M,N] = A[M,K] @ Bt[N,K]^T --------------------------
// BK=64 (32 KB LDS, 32 MFMA per barrier pair). XOR-swizzled LDS columns:
// LDS slot (row, cb) holds global col-block cb^(row&7) -> conflict-free
// ds_read_b128 fragment reads; global_load_lds dest stays lane*16-contiguous.
// 1-D grid with XCD swizzle: flat = (y%8) + 8*(x + gx*(y/8)) so all col-tiles
// of one M-row share an XCD L2 (A-tile fetched once per XCD).
// MFMA operands swapped (mfma(bfr, af)): lane's 4 acc regs = 4 consecutive
// N-cols of one M-row: row = m0+wm+i*16+l16, col = n0+wn+j*16+quad*4+r.
// MODE 0: qkv scatter (q*0.125 -> [nh][S][64]; k -> [nh][8][S][8] chunked;
//         v -> [nh][128][64][8] chunked)
// MODE 1/3: outf = acc + bias + resid (float4)
// MODE 2: ob0 = bf16(gelu_tanh(acc + bias))
template <int MODE>
__global__ __launch_bounds__(256) void gemm_bt(
    const bf16* __restrict__ A, const bf16* __restrict__ Bt,
    const float* __restrict__ bias, const float* __restrict__ resid,
    float* __restrict__ outf, bf16* __restrict__ ob0, bf16* __restrict__ ob1,
    bf16* __restrict__ ob2, int M, int N, int K) {
  __shared__ bf16 As[128 * 64];
  __shared__ bf16 Bs[128 * 64];
  int tid = threadIdx.x;
  int wave = tid >> 6, lane = tid & 63;
  int quad = lane >> 4, l16 = lane & 15;
  int gx = N >> 7;
  int flat = blockIdx.x;
  int y8 = flat & 7;
  int q2 = flat >> 3;
  int bx = q2 % gx;
  int by = (q2 / gx) * 8 + y8;
  int m0 = by * 128, n0 = bx * 128;
  int wm = (wave & 1) * 64, wn = (wave >> 1) * 64;
  f32x4 acc[4][4];
  for (int i = 0; i < 4; i++)
    for (int j = 0; j < 4; j++)
      for (int r = 0; r < 4; r++) acc[i][j][r] = 0.f;

  int xs = l16 & 7;                 // fragment-read XOR key

  for (int kb = 0; kb < K; kb += 64) {
    __syncthreads();
#pragma unroll
    for (int t = 0; t < 4; ++t) {
      int c = t * 256 + tid;        // 16B chunk id; LDS dest = c*16 bytes
      int row = c >> 3;
      int cg = (((c & 7) ^ (row & 7)) << 3);   // swizzled global col (elems)
      async_cp16(A  + (size_t)(m0 + row) * K + kb + cg, &As[c * 8]);
      async_cp16(Bt + (size_t)(n0 + row) * K + kb + cg, &Bs[c * 8]);
    }
    __syncthreads();
#pragma unroll
    for (int ks = 0; ks < 2; ks++) {
      short8 af[4], bfr[4];
      for (int i = 0; i < 4; i++)
        af[i] = *(const short8*)
            &As[(wm + i * 16 + l16) * 64 + (((ks * 4 + quad) ^ xs) << 3)];
      for (int j = 0; j < 4; j++)
        bfr[j] = *(const short8*)
            &Bs[(wn + j * 16 + l16) * 64 + (((ks * 4 + quad) ^ xs) << 3)];
      for (int i = 0; i < 4; i++)
        for (int j = 0; j < 4; j++)
          acc[i][j] = __builtin_amdgcn_mfma_f32_16x16x32_bf16(bfr[j], af[i],
                                                              acc[i][j], 0, 0, 0);
    }
  }

  for (int j = 0; j < 4; j++) {
    int colb = n0 + wn + j * 16 + quad * 4;          // 4 consecutive cols
    f32x4 b4 = *(const f32x4*)&bias[colb];
    for (int i = 0; i < 4; i++) {
      int row = m0 + wm + i * 16 + l16;
      f32x4 v = acc[i][j] + b4;
      if (MODE == 0) {
        int nn = row >> 10, s = row & 1023;
        if (colb < 768) {
          int h = colb >> 6, db = colb & 63;
          short4v pk;
          for (int r = 0; r < 4; r++)
            pk[r] = __builtin_bit_cast(short, __float2bfloat16(v[r] * 0.125f));
          *(short4v*)&ob0[(((size_t)nn * H_N + h) * S_LEN + s) * 64 + db] = pk;
        } else if (colb < 1536) {
          int c = colb - 768;
          size_t nh2 = (size_t)nn * H_N + (c >> 6);
          int d = c & 63;
          short4v pk;
          for (int r = 0; r < 4; r++)
            pk[r] = __builtin_bit_cast(short, __float2bfloat16(v[r]));
          *(short4v*)&ob1[((nh2 * 8 + (d >> 3)) * S_LEN + s) * 8 + (d & 7)] = pk;
        } else {
          int c = colb - 1536;
          size_t nh2 = (size_t)nn * H_N + (c >> 6);
          int d0 = c & 63;
          for (int r = 0; r < 4; r++)
            ob2[((nh2 * 128 + (s >> 3)) * 64 + d0 + r) * 8 + (s & 7)] =
                __float2bfloat16(v[r]);
        }
      } else if (MODE == 1 || MODE == 3) {
        size_t idx = (size_t)row * N + colb;
        f32x4 rv = *(const f32x4*)&resid[idx];
        *(f32x4*)&outf[idx] = v + rv;
      } else if (MODE == 2) {
        short4v pk;
        for (int r = 0; r < 4; r++) {
          float x = v[r];
          // tanh-form GELU: x * sigmoid(1.5957691*(x + 0.044715 x^3))
          float t = x * (1.59576912161f + 0.0713548162726f * x * x);
          float g = x * __builtin_amdgcn_rcpf(1.0f + __expf(-t));
          pk[r] = __builtin_bit_cast(short, __float2bfloat16(g));
        }
        *(short4v*)&ob0[(size_t)row * N + colb] = pk;
      }
    }
  }
}

// ---------------- flash attention v2: S^T trick, causal; q pre-scaled --------
// q:  [nh][1024][64] bf16
// kg: [nh][8][1024][8]  chunked K
// vg: [nh][128][64][8]  chunked V (kpos-chunked)
// out: [N,S,E] bf16
__global__ __launch_bounds__(256) void attn_fwd(
    const bf16* __restrict__ q, const bf16* __restrict__ kg,
    const bf16* __restrict__ vg, bf16* __restrict__ out) {
  __shared__ bf16 kt2[8 * 64 * 8];   // [dc][kpos][8din]   8 KB
  __shared__ bf16 vt2[8 * 64 * 8];   // [kc][d][8kin]      8 KB
  __shared__ bf16 pb[4][16 * 68];    // per-wave P[q][kpos], stride 68 (pad)
  int qt = blockIdx.x;               // q tile of 64
  int nh = blockIdx.y;
  int n = nh / H_N, h = nh % H_N;
  int tid = threadIdx.x, wave = tid >> 6, lane = tid & 63;
  int quad = lane >> 4, l16 = lane & 15;
  const bf16* qp = q  + (size_t)nh * S_LEN * 64;
  const bf16* kp = kg + (size_t)nh * 8 * S_LEN * 8;
  const bf16* vp = vg + (size_t)nh * 128 * 64 * 8;
  int qrow = qt * 64 + wave * 16;    // wave's 16 q rows; lane's q = qrow + l16

  short8 qf[2];
  qf[0] = *(const short8*)&qp[(size_t)(qrow + l16) * 64 + quad * 8];
  qf[1] = *(const short8*)&qp[(size_t)(qrow + l16) * 64 + 32 + quad * 8];

  f32x4 oa[4];                       // O^T: d = dt*16+quad*4+r, q = l16
  for (int dt = 0; dt < 4; dt++)
    for (int r = 0; r < 4; r++) oa[dt][r] = 0.f;
  float mi = -INFINITY, li = 0.f;    // per-lane: one q row each

  for (int kb = 0; kb <= qt; ++kb) {
    __syncthreads();
    for (int t = 0; t < 2; ++t) {
      int s = t * 256 + tid;         // 16B slot index; uniform base + lane*16
      int c = s >> 6, e = s & 63;    // kt2: c=dchunk,e=kpos ; vt2: c=kchunk,e=d
      async_cp16(kp + ((size_t)c * S_LEN + kb * 64 + e) * 8, &kt2[(size_t)s * 8]);
      async_cp16(vp + ((size_t)(kb * 8 + c) * 64 + e) * 8, &vt2[(size_t)s * 8]);
    }
    __syncthreads();

    // S^T[kpos][q] = K·Q^T : lane holds q=l16, kpos = nt*16+quad*4+r
    f32x4 sa[4];
    for (int nt = 0; nt < 4; nt++) {
      for (int r = 0; r < 4; r++) sa[nt][r] = 0.f;
      for (int ks = 0; ks < 2; ks++) {
        short8 kf = *(const short8*)
            &kt2[(size_t)((ks * 4 + quad) * 64 + nt * 16 + l16) * 8];
        sa[nt] = __builtin_amdgcn_mfma_f32_16x16x32_bf16(kf, qf[ks], sa[nt], 0, 0, 0);
      }
    }
    if (kb == qt) {  // diagonal: mask kpos_local > q_local
      int ql = wave * 16 + l16;
      for (int nt = 0; nt < 4; nt++)
        for (int r = 0; r < 4; r++)
          if (nt * 16 + quad * 4 + r > ql) sa[nt][r] = -INFINITY;
    }
    // online softmax: all 16 score values for this lane's q are in-register;
    // full-64 reduction = 2 shuffles across quads (xor 16, 32)
    float mx = sa[0][0];
    for (int nt = 0; nt < 4; nt++)
      for (int r = 0; r < 4; r++) mx = fmaxf(mx, sa[nt][r]);
    mx = fmaxf(mx, __shfl_xor(mx, 16));
    mx = fmaxf(mx, __shfl_xor(mx, 32));
    float mn = fmaxf(mi, mx);
    float alpha = __expf(mi - mn);
    float rs = 0.f;
    for (int nt = 0; nt < 4; nt++)
      for (int r = 0; r < 4; r++) {
        float p = __expf(sa[nt][r] - mn);
        sa[nt][r] = p;
        rs += p;
      }
    rs += __shfl_xor(rs, 16);
    rs += __shfl_xor(rs, 32);
    li = li * alpha + rs;
    mi = mn;
    for (int dt = 0; dt < 4; dt++)
      for (int r = 0; r < 4; r++) oa[dt][r] *= alpha;

    // P write: lane's 4 regs of sa[nt] are 4 consecutive kpos for row q=l16
    bf16* pw = pb[wave];
    for (int nt = 0; nt < 4; nt++) {
      short4v pk;
      for (int r = 0; r < 4; r++)
        pk[r] = __builtin_bit_cast(short, __float2bfloat16(sa[nt][r]));
      *(short4v*)&pw[l16 * 68 + nt * 16 + quad * 4] = pk;
    }
    asm volatile("s_waitcnt lgkmcnt(0)" ::: "memory");  // same-wave LDS RAW

    // O^T[d][q] += V^T·P^T : A = V^T frag (chunked vt2), B = P row-major frag
    for (int ks = 0; ks < 2; ks++) {
      short8 pf = *(const short8*)&pw[l16 * 68 + ks * 32 + quad * 8];
      for (int dt = 0; dt < 4; dt++) {
        short8 vf = *(const short8*)
            &vt2[(size_t)((ks * 4 + quad) * 64 + dt * 16 + l16) * 8];
        oa[dt] = __builtin_amdgcn_mfma_f32_16x16x32_bf16(vf, pf, oa[dt], 0, 0, 0);
      }
    }
  }

  float inv = 1.0f / li;
  int token = n * S_LEN + qrow + l16;
  for (int dt = 0; dt < 4; dt++) {
    short4v ov;
    for (int r = 0; r < 4; r++)
      ov[r] = __builtin_bit_cast(short, __float2bfloat16(oa[dt][r] * inv));
    *(short4v*)&out[(size_t)token * E_DIM + h * 64 + dt * 16 + quad * 4] = ov;
  }
}

extern "C" void kernel_launch(void* const* d_in, const int* in_sizes, int n_in,
                              void* d_out, int out_size, void* d_ws, size_t ws_size,
                              hipStream_t stream) {
  (void)in_sizes; (void)n_in; (void)out_size; (void)ws_size;
  const float* x      = (const float*)d_in[0];
  const float* ln1_g  = (const float*)d_in[1];
  const float* ln1_b  = (const float*)d_in[2];
  const float* ln2_g  = (const float*)d_in[3];
  const float* ln2_b  = (const float*)d_in[4];
  const float* w_attn = (const float*)d_in[5];
  const float* b_attn = (const float*)d_in[6];
  const float* w_proj = (const float*)d_in[7];
  const float* b_proj = (const float*)d_in[8];
  const float* w_fc   = (const float*)d_in[9];
  const float* b_fc   = (const float*)d_in[10];
  const float* w_fc2  = (const float*)d_in[11];
  const float* b_fc2  = (const float*)d_in[12];
  float* out = (float*)d_out;

  char* ws = (char*)d_ws;
  bf16* wt_attn = (bf16*)(ws);                 //  3,538,944 B
  bf16* wt_proj = (bf16*)(ws + 3538944);       //  1,179,648 B
  bf16* wt_fc   = (bf16*)(ws + 4718592);       //  4,718,592 B
  bf16* wt_fc2  = (bf16*)(ws + 9437184);       //  4,718,592 B
  bf16* hbuf    = (bf16*)(ws + 14155776);      // 12,582,912 B
  float* x2     = (float*)(ws + 26738688);     // 25,165,824 B
  bf16* qb      = (bf16*)(ws + 51904512);      // 12,582,912 B
  bf16* kbuf    = (bf16*)(ws + 64487424);      // 12,582,912 B (chunked kg)
  bf16* vtb     = (bf16*)(ws + 77070336);      // 12,582,912 B (chunked vg)
  bf16* ao      = (bf16*)(ws + 89653248);      // 12,582,912 B  (ends 102,236,160)
  bf16* ff      = qb;  // reuse q/k/v/ao region (50,331,648 B needed)

  dim3 blk(256);
  wcastT<<<dim3(2304 / 32, 768 / 32), blk, 0, stream>>>(w_attn, wt_attn, 768, 2304);
  wcastT<<<dim3(768 / 32, 768 / 32), blk, 0, stream>>>(w_proj, wt_proj, 768, 768);
  wcastT<<<dim3(3072 / 32, 768 / 32), blk, 0, stream>>>(w_fc, wt_fc, 768, 3072);
  wcastT<<<dim3(768 / 32, 3072 / 32), blk, 0, stream>>>(w_fc2, wt_fc2, 3072, 768);

  ln_rows<<<8192, blk, 0, stream>>>(x, ln1_g, ln1_b, hbuf);

  gemm_bt<0><<<dim3(18 * 64), blk, 0, stream>>>(
      hbuf, wt_attn, b_attn, nullptr, nullptr, qb, kbuf, vtb, 8192, 2304, 768);

  attn_fwd<<<dim3(16, 96), blk, 0, stream>>>(qb, kbuf, vtb, ao);

  gemm_bt<1><<<dim3(6 * 64), blk, 0, stream>>>(
      ao, wt_proj, b_proj, x, x2, nullptr, nullptr, nullptr, 8192, 768, 768);

  ln_rows<<<8192, blk, 0, stream>>>(x2, ln2_g, ln2_b, hbuf);

  gemm_bt<2><<<dim3(24 * 64), blk, 0, stream>>>(
      hbuf, wt_fc, b_fc, nullptr, nullptr, ff, nullptr, nullptr, 8192, 3072, 768);

  gemm_bt<3><<<dim3(6 * 64), blk, 0, stream>>>(
      ff, wt_fc2, b_fc2, x2, out, nullptr, nullptr, nullptr, 8192, 768, 3072);
}